// Round 6
// baseline (46180.215 us; speedup 1.0000x reference)
//
#include <hip/hip_runtime.h>
#include <hip/hip_bf16.h>
#include <math.h>

#ifndef M_PIf
#define M_PIf 3.14159265358979323846f
#endif

static constexpr int kNFFT = 2048;
static constexpr int kHOP  = 512;
static constexpr int kBINS = 1025;
static constexpr int kT    = 862;     // frames == sequence length
static constexpr int kL    = 441000;
static constexpr int kB    = 4;
static constexpr int kNSIG = 8;       // B * 2 channels
static constexpr int kD    = 2050;
static constexpr int kHD   = 1025;    // head dim
static constexpr int kDFF  = 8200;
static constexpr int kBS   = kB * kT; // 3448 token rows
static constexpr int kD3   = 3 * kD;  // 6150
static constexpr float kAttnScale = 0.031234752377721214f; // 1/sqrt(1025)
static constexpr long kQK  = (long)kT * kHD;   // 883,550
static constexpr long kS2  = (long)kT * kT;    // 743,044

using bf16 = __hip_bfloat16;

__device__ __forceinline__ float ldf(const float* p, long i) { return p[i]; }
__device__ __forceinline__ float ldf(const bf16* p, long i) {
  return __bfloat162float(p[i]);
}
__device__ __forceinline__ void sto(float* p, long i, float v) { p[i] = v; }
__device__ __forceinline__ void sto(bf16* p, long i, float v) {
  p[i] = __float2bfloat16(v);
}

// ---------------------------------------------------------------------------
// 2048-point radix-2 Stockham FFT in LDS (natural order in/out).
// ---------------------------------------------------------------------------
__device__ __forceinline__ void fft2048_lds(float*& sr, float*& si,
                                            float* dr, float* di,
                                            int tid, float dir) {
  int s = 0;
  for (int Ns = 1; Ns < 2048; Ns <<= 1, ++s) {
#pragma unroll
    for (int q = 0; q < 4; ++q) {
      int j = tid + q * 256;          // 0..1023
      int base = j & (Ns - 1);
      int grp = j >> s;
      float ang = dir * M_PIf * (float)base / (float)Ns;
      float c, sn;
      sincosf(ang, &sn, &c);
      float ar = sr[j],       ai = si[j];
      float br = sr[j + 1024], bi = si[j + 1024];
      float tbr = br * c - bi * sn;
      float tbi = br * sn + bi * c;
      int o = (grp << (s + 1)) + base;
      dr[o]      = ar + tbr;  di[o]      = ai + tbi;
      dr[o + Ns] = ar - tbr;  di[o + Ns] = ai - tbi;
    }
    __syncthreads();
    float* t0 = sr; sr = dr; dr = t0;
    float* t1 = si; si = di; di = t1;
  }
}

// STFT: one block per (frame, signal). Writes interleaved (re,im) into out1.
__global__ __launch_bounds__(256) void k_stft(const float* __restrict__ mix,
                                              const float* __restrict__ win,
                                              float* __restrict__ spec) {
  __shared__ float b0r[2048], b0i[2048], b1r[2048], b1i[2048];
  int t = blockIdx.x, sig = blockIdx.y, tid = threadIdx.x;
  const float* x = mix + (long)sig * kL;
  for (int i = tid; i < 2048; i += 256) {
    int src = t * kHOP + i - 1024;
    if (src < 0) src = -src;
    if (src >= kL) src = 2 * kL - 2 - src;
    b0r[i] = x[src] * win[i];
    b0i[i] = 0.f;
  }
  __syncthreads();
  float* sr = b0r; float* si = b0i;
  fft2048_lds(sr, si, b1r, b1i, tid, -1.f);
  for (int k = tid; k < kBINS; k += 256) {
    long o = ((long)sig * kBINS + k) * kT + t;
    spec[o * 2]     = sr[k];
    spec[o * 2 + 1] = si[k];
  }
}

// iSTFT per-frame from interleaved spec: hermitian extend, iFFT, window.
__global__ __launch_bounds__(256) void k_istft(const float* __restrict__ spec,
                                               const float* __restrict__ win,
                                               float* __restrict__ frames) {
  __shared__ float b0r[2048], b0i[2048], b1r[2048], b1i[2048];
  int t = blockIdx.x, sig = blockIdx.y, tid = threadIdx.x;
  for (int k = tid; k < kBINS; k += 256) {
    long o = ((long)sig * kBINS + k) * kT + t;
    b0r[k] = spec[o * 2];
    b0i[k] = spec[o * 2 + 1];
  }
  __syncthreads();
  for (int k = 1025 + tid; k < 2048; k += 256) {
    b0r[k] = b0r[2048 - k];
    b0i[k] = -b0i[2048 - k];
  }
  __syncthreads();
  float* sr = b0r; float* si = b0i;
  fft2048_lds(sr, si, b1r, b1i, tid, +1.f);
  const float scale = 1.f / 2048.f;
  float* fo = frames + ((long)sig * kT + t) * 2048;
  for (int n = tid; n < 2048; n += 256) fo[n] = sr[n] * scale * win[n];
}

// Deterministic overlap-add gather (<=4 frames per output sample) + wsq div.
__global__ void k_gather(const float* __restrict__ frames,
                         const float* __restrict__ win,
                         float* __restrict__ out0) {
  long idx = (long)blockIdx.x * 256 + threadIdx.x;
  long total = (long)kNSIG * kL;
  if (idx >= total) return;
  int sig = (int)(idx / kL);
  int l = (int)(idx % kL);
  int j = l + 1024;
  int tmax = j >> 9; if (tmax > kT - 1) tmax = kT - 1;
  int v = j - 1536;
  int tmin = v > 0 ? (v >> 9) : 0;
  float acc = 0.f, w2 = 0.f;
  for (int t = tmin; t <= tmax; ++t) {
    int n = j - (t << 9);
    float w = win[n];
    acc += frames[((long)sig * kT + t) * 2048 + n];
    w2 = fmaf(w, w, w2);
  }
  out0[idx] = acc / (w2 > 1e-11f ? w2 : 1.f);
}

// conv1x1 (complex, per-channel) + transpose to (B,T,D) + positional enc.
__global__ void k_conv1_pe(const float* __restrict__ spec,
                           const float* __restrict__ c1wr, const float* __restrict__ c1br,
                           const float* __restrict__ c1wi, const float* __restrict__ c1bi,
                           float* __restrict__ xr, float* __restrict__ xi) {
  long idx = (long)blockIdx.x * 256 + threadIdx.x;
  long total = (long)kB * 2 * kBINS * kT;
  if (idx >= total) return;
  int t = (int)(idx % kT);
  long r0 = idx / kT;
  int bin = (int)(r0 % kBINS);
  long r1 = r0 / kBINS;
  int ch = (int)(r1 % 2);
  int b = (int)(r1 / 2);
  float re = spec[idx * 2], im = spec[idx * 2 + 1];
  float wr = c1wr[ch], br = c1br[ch], wi = c1wi[ch], bi = c1bi[ch];
  float nr = (re * wr + br) - (im * wi + bi);
  float ni = (im * wr + br) + (re * wi + bi);
  int d = bin * 2 + ch;
  int k = d >> 1;
  float dv = expf((float)k * (-9.210340371976184f / 1025.0f));
  float arg = (float)t * dv;
  float pe = (d & 1) ? cosf(arg) : sinf(arg);
  long ro = ((long)(b * kT + t)) * kD + d;
  xr[ro] = nr + pe;
  xi[ro] = ni + pe;
}

// ---------------------------------------------------------------------------
// Mixed-dtype GEMM, fp32 accumulate. A: MxK row-major (lda). BMODE=0:
// C = A*B^T, B is NxK (ldb); BMODE=1: B is KxN (ldb). Epilogue:
// v = sign*dot + bscale*bias[n]; if accum v += C; if relu v = max(v,0).
// ---------------------------------------------------------------------------
template <int BMODE, typename TA, typename TB, typename TC>
__global__ __launch_bounds__(256) void k_gemm(
    const TA* __restrict__ A, const TB* __restrict__ B,
    TC* __restrict__ C, const float* __restrict__ bias,
    int M, int N, int K, int lda, int ldb, int ldc,
    float sign, float bscale, int accum, int relu) {
  __shared__ __align__(16) float As[16][64];
  __shared__ __align__(16) float Bs[16][64];
  int tid = threadIdx.x;
  int tx = tid & 15, ty = tid >> 4;
  int bm = blockIdx.y * 64, bn = blockIdx.x * 64;
  float acc[4][4] = {};
  for (int k0 = 0; k0 < K; k0 += 16) {
    {
      int row = tid >> 2, kq = (tid & 3) * 4;
      int gm = bm + row;
#pragma unroll
      for (int e = 0; e < 4; ++e) {
        int gk = k0 + kq + e;
        As[kq + e][row] = (gm < M && gk < K) ? ldf(A, (long)gm * lda + gk) : 0.f;
      }
    }
    if (BMODE == 0) {
      int row = tid >> 2, kq = (tid & 3) * 4;
      int gn = bn + row;
#pragma unroll
      for (int e = 0; e < 4; ++e) {
        int gk = k0 + kq + e;
        Bs[kq + e][row] = (gn < N && gk < K) ? ldf(B, (long)gn * ldb + gk) : 0.f;
      }
    } else {
      int kk = tid >> 4, nq = (tid & 15) * 4;
#pragma unroll
      for (int e = 0; e < 4; ++e) {
        int gn = bn + nq + e;
        Bs[kk][nq + e] =
            ((k0 + kk) < K && gn < N) ? ldf(B, (long)(k0 + kk) * ldb + gn) : 0.f;
      }
    }
    __syncthreads();
#pragma unroll
    for (int kk = 0; kk < 16; ++kk) {
      const float4 av = *(const float4*)&As[kk][ty * 4];
      const float4 bv = *(const float4*)&Bs[kk][tx * 4];
      float a4[4] = {av.x, av.y, av.z, av.w};
      float b4[4] = {bv.x, bv.y, bv.z, bv.w};
#pragma unroll
      for (int i = 0; i < 4; ++i)
#pragma unroll
        for (int jj = 0; jj < 4; ++jj)
          acc[i][jj] = fmaf(a4[i], b4[jj], acc[i][jj]);
    }
    __syncthreads();
  }
#pragma unroll
  for (int i = 0; i < 4; ++i) {
    int gm = bm + ty * 4 + i;
    if (gm >= M) continue;
#pragma unroll
    for (int jj = 0; jj < 4; ++jj) {
      int gn = bn + tx * 4 + jj;
      if (gn >= N) continue;
      float v = sign * acc[i][jj];
      if (bias) v += bscale * bias[gn];
      long co = (long)gm * ldc + gn;
      if (accum) v += ldf(C, co);
      if (relu) v = fmaxf(v, 0.f);
      sto(C, co, v);
    }
  }
}

// Per-head fused softmax over 4 fp32 score mats (stride kS2) + fold into
// 3 bf16 prob mats: P0=M1=Arr-Aii, P1=M2p=Ari+Air, P2=M2m=Ari-Air.
__global__ __launch_bounds__(256) void k_smf(const float* __restrict__ S,
                                             bf16* __restrict__ P) {
  long rbase = (long)blockIdx.x * kT;
  int tid = threadIdx.x;
  int lane = tid & 63, w = tid >> 6;
  float v[4][4];
  float mx[4] = {-3.4e38f, -3.4e38f, -3.4e38f, -3.4e38f};
#pragma unroll
  for (int c = 0; c < 4; ++c) {
    const float* row = S + c * kS2 + rbase;
#pragma unroll
    for (int q = 0; q < 4; ++q) {
      int i = tid + q * 256;
      v[c][q] = (i < kT) ? row[i] : -3.4e38f;
      mx[c] = fmaxf(mx[c], v[c][q]);
    }
  }
  __shared__ float redm[4][4];
  for (int o = 32; o > 0; o >>= 1)
#pragma unroll
    for (int c = 0; c < 4; ++c) mx[c] = fmaxf(mx[c], __shfl_down(mx[c], o));
  if (lane == 0)
#pragma unroll
    for (int c = 0; c < 4; ++c) redm[w][c] = mx[c];
  __syncthreads();
#pragma unroll
  for (int c = 0; c < 4; ++c)
    mx[c] = fmaxf(fmaxf(redm[0][c], redm[1][c]), fmaxf(redm[2][c], redm[3][c]));
  __syncthreads();
  float sm[4] = {0.f, 0.f, 0.f, 0.f};
#pragma unroll
  for (int c = 0; c < 4; ++c)
#pragma unroll
    for (int q = 0; q < 4; ++q) {
      int i = tid + q * 256;
      if (i < kT) {
        v[c][q] = expf(kAttnScale * (v[c][q] - mx[c]));
        sm[c] += v[c][q];
      }
    }
  __shared__ float reds[4][4];
  for (int o = 32; o > 0; o >>= 1)
#pragma unroll
    for (int c = 0; c < 4; ++c) sm[c] += __shfl_down(sm[c], o);
  if (lane == 0)
#pragma unroll
    for (int c = 0; c < 4; ++c) reds[w][c] = sm[c];
  __syncthreads();
  float inv[4];
#pragma unroll
  for (int c = 0; c < 4; ++c)
    inv[c] = 1.f / (reds[0][c] + reds[1][c] + reds[2][c] + reds[3][c]);
  bf16* p0 = P + rbase;
  bf16* p1 = P + kS2 + rbase;
  bf16* p2 = P + 2 * kS2 + rbase;
#pragma unroll
  for (int q = 0; q < 4; ++q) {
    int i = tid + q * 256;
    if (i >= kT) continue;
    float a0 = v[0][q] * inv[0], a1 = v[1][q] * inv[1];
    float a2 = v[2][q] * inv[2], a3 = v[3][q] * inv[3];
    p0[i] = __float2bfloat16(a0 - a3);
    p1[i] = __float2bfloat16(a1 + a2);
    p2[i] = __float2bfloat16(a1 - a2);
  }
}

// LayerNorm over rows of length d, in place (fp32).
__global__ __launch_bounds__(256) void k_ln(float* __restrict__ X,
                                            const float* __restrict__ g,
                                            const float* __restrict__ b, int d) {
  long row = blockIdx.x;
  float* x = X + row * d;
  int tid = threadIdx.x;
  float s = 0.f, s2 = 0.f;
  for (int i = tid; i < d; i += 256) {
    float v = x[i];
    s += v;
    s2 = fmaf(v, v, s2);
  }
  __shared__ float rs[4], rs2[4];
  for (int o = 32; o > 0; o >>= 1) {
    s += __shfl_down(s, o);
    s2 += __shfl_down(s2, o);
  }
  int lane = tid & 63, w = tid >> 6;
  if (lane == 0) { rs[w] = s; rs2[w] = s2; }
  __syncthreads();
  float st = rs[0] + rs[1] + rs[2] + rs[3];
  float s2t = rs2[0] + rs2[1] + rs2[2] + rs2[3];
  float m = st / d;
  float var = s2t / d - m * m;
  float inv = rsqrtf(var + 1e-5f);
  for (int i = tid; i < d; i += 256) x[i] = (x[i] - m) * inv * g[i] + b[i];
}

// Final complex conv1x1 mask + sigmoid gating of spec (in-place in out1).
__global__ void k_mask(const float* __restrict__ gr_, const float* __restrict__ gi_,
                       const float* __restrict__ c2wr, const float* __restrict__ c2br,
                       const float* __restrict__ c2wi, const float* __restrict__ c2bi,
                       float* __restrict__ spec) {
  long idx = (long)blockIdx.x * 256 + threadIdx.x;
  long total = (long)kB * 2 * kBINS * kT;
  if (idx >= total) return;
  int t = (int)(idx % kT);
  long r0 = idx / kT;
  int bin = (int)(r0 % kBINS);
  long r1 = r0 / kBINS;
  int ch = (int)(r1 % 2);
  int b = (int)(r1 / 2);
  long ro = ((long)(b * kT + t)) * kD + (bin * 2 + ch);
  float gr = gr_[ro], gi = gi_[ro];
  float wr = c2wr[ch], br = c2br[ch], wi = c2wi[ch], bi = c2bi[ch];
  float mr = (gr * wr + br) - (gi * wi + bi);
  float mi = (gi * wr + br) + (gr * wi + bi);
  float re = spec[idx * 2], im = spec[idx * 2 + 1];
  spec[idx * 2]     = re / (1.f + expf(-mr));
  spec[idx * 2 + 1] = im / (1.f + expf(-mi));
}

extern "C" void kernel_launch(void* const* d_in, const int* in_sizes, int n_in,
                              void* d_out, int out_size, void* d_ws, size_t ws_size,
                              hipStream_t stream) {
  const float* mix        = (const float*)d_in[0];
  const float* window     = (const float*)d_in[1];
  const float* c1wr       = (const float*)d_in[2];
  const float* c1br       = (const float*)d_in[3];
  const float* c1wi       = (const float*)d_in[4];
  const float* c1bi       = (const float*)d_in[5];
  const float* c2wr       = (const float*)d_in[6];
  const float* c2br       = (const float*)d_in[7];
  const float* c2wi       = (const float*)d_in[8];
  const float* c2bi       = (const float*)d_in[9];
  const float* attn_in_w  = (const float*)d_in[10];
  const float* attn_in_b  = (const float*)d_in[11];
  const float* attn_out_w = (const float*)d_in[12];
  const float* attn_out_b = (const float*)d_in[13];
  const float* l1wr       = (const float*)d_in[14];
  const float* l1br       = (const float*)d_in[15];
  const float* l1wi       = (const float*)d_in[16];
  const float* l1bi       = (const float*)d_in[17];
  const float* l2wr       = (const float*)d_in[18];
  const float* l2br       = (const float*)d_in[19];
  const float* l2wi       = (const float*)d_in[20];
  const float* l2bi       = (const float*)d_in[21];
  const float* n1_gr      = (const float*)d_in[22];
  const float* n1_br      = (const float*)d_in[23];
  const float* n1_gi      = (const float*)d_in[24];
  const float* n1_bi      = (const float*)d_in[25];
  const float* n2_gr      = (const float*)d_in[26];
  const float* n2_br      = (const float*)d_in[27];
  const float* n2_gi      = (const float*)d_in[28];
  const float* n2_bi      = (const float*)d_in[29];

  // ---- Workspace arenas (bytes). Total 169,641,600 B (< 188.9 MB proven).
  // [T 56,547,200][O 56,547,200][S 34,017,968][PAD 22,529,232]
  char* wsb = (char*)d_ws;
  const size_t oT   = 0;
  const size_t oO   = 56547200;
  const size_t oS   = 113094400;
  const size_t kNeed = 169641600;
  if (ws_size < kNeed) return;  // fail signature: out0 all-zero (2.578125)

  float* xr  = (float*)(wsb + oT);            // tokens r (later: proj/FFN2 out)
  float* xi  = xr + 7068400L;
  float* or_ = (float*)(wsb + oO);            // attention out r (fp32)
  float* oi  = or_ + 7068400L;
  // per-head scratch inside S:
  float* qr = (float*)(wsb + oS);             // 883,550 f32 each
  float* qi = qr + kQK;
  float* kr = qi + kQK;
  float* ki = kr + kQK;
  bf16*  vr = (bf16*)(wsb + oS + 14136800);   // 883,550 bf16 each
  bf16*  vi = (bf16*)(wsb + oS + 15903900);
  float* sS = (float*)(wsb + oS + 17671000);  // 4 x 743,044 f32
  bf16*  sP = (bf16*)(wsb + oS + 29559704);   // 3 x 743,044 bf16
  // phase-2 overlays:
  bf16*  hr = (bf16*)(wsb + oO);              // 28,273,600 bf16 = O arena
  bf16*  hi = (bf16*)(wsb + oS);              // 28,273,600 bf16 = S+PAD
  float* frames = (float*)(wsb + oO);         // 14,123,008 f32 (< O arena)

  float* out0 = (float*)d_out;
  float* spec = out0 + (long)kNSIG * kL;  // out1: interleaved (re,im)

  auto gemm_fff = [&](int bmode, const float* A, const float* Bm, float* C,
                      const float* bias, int M, int N, int K, int lda, int ldb,
                      int ldc, float sign, float bscale, int accum, int relu) {
    dim3 g((N + 63) / 64, (M + 63) / 64, 1);
    if (bmode == 0)
      k_gemm<0, float, float, float><<<g, 256, 0, stream>>>(
          A, Bm, C, bias, M, N, K, lda, ldb, ldc, sign, bscale, accum, relu);
    else
      k_gemm<1, float, float, float><<<g, 256, 0, stream>>>(
          A, Bm, C, bias, M, N, K, lda, ldb, ldc, sign, bscale, accum, relu);
  };

  // 1) STFT -> spec (out1)
  k_stft<<<dim3(kT, kNSIG), 256, 0, stream>>>(mix, window, spec);

  // 2) conv1 + pos-enc -> fp32 tokens (T arena)
  long nct = (long)kB * 2 * kBINS * kT;
  k_conv1_pe<<<(nct + 255) / 256, 256, 0, stream>>>(spec, c1wr, c1br, c1wi,
                                                    c1bi, xr, xi);

  // 3) streaming attention, one (b,h) at a time; fp32 Q/K/scores.
  for (int b = 0; b < kB; ++b) {
    const float* xrb = xr + (long)b * kT * kD;
    const float* xib = xi + (long)b * kT * kD;
    for (int h = 0; h < 2; ++h) {
      const float* Wq = attn_in_w + (long)(h * kHD) * kD;
      const float* Wk = attn_in_w + (long)(kD + h * kHD) * kD;
      const float* Wv = attn_in_w + (long)(2 * kD + h * kHD) * kD;
      const float* bq = attn_in_b + h * kHD;
      const float* bk = attn_in_b + kD + h * kHD;
      const float* bv = attn_in_b + 2 * kD + h * kHD;
      dim3 gp((kHD + 63) / 64, (kT + 63) / 64, 1);
      // projections: Q,K fp32; V bf16
      k_gemm<0, float, float, float><<<gp, 256, 0, stream>>>(
          xrb, Wq, qr, bq, kT, kHD, kD, kD, kD, kHD, 1.f, 1.f, 0, 0);
      k_gemm<0, float, float, float><<<gp, 256, 0, stream>>>(
          xib, Wq, qi, bq, kT, kHD, kD, kD, kD, kHD, 1.f, 1.f, 0, 0);
      k_gemm<0, float, float, float><<<gp, 256, 0, stream>>>(
          xrb, Wk, kr, bk, kT, kHD, kD, kD, kD, kHD, 1.f, 1.f, 0, 0);
      k_gemm<0, float, float, float><<<gp, 256, 0, stream>>>(
          xib, Wk, ki, bk, kT, kHD, kD, kD, kD, kHD, 1.f, 1.f, 0, 0);
      k_gemm<0, float, float, bf16><<<gp, 256, 0, stream>>>(
          xrb, Wv, vr, bv, kT, kHD, kD, kD, kD, kHD, 1.f, 1.f, 0, 0);
      k_gemm<0, float, float, bf16><<<gp, 256, 0, stream>>>(
          xib, Wv, vi, bv, kT, kHD, kD, kD, kD, kHD, 1.f, 1.f, 0, 0);
      // scores: rr, ri, ir, ii (fp32)
      dim3 gs((kT + 63) / 64, (kT + 63) / 64, 1);
      k_gemm<0, float, float, float><<<gs, 256, 0, stream>>>(
          qr, kr, sS,          nullptr, kT, kT, kHD, kHD, kHD, kT, 1.f, 0.f, 0, 0);
      k_gemm<0, float, float, float><<<gs, 256, 0, stream>>>(
          qr, ki, sS + kS2,    nullptr, kT, kT, kHD, kHD, kHD, kT, 1.f, 0.f, 0, 0);
      k_gemm<0, float, float, float><<<gs, 256, 0, stream>>>(
          qi, kr, sS + 2*kS2,  nullptr, kT, kT, kHD, kHD, kHD, kT, 1.f, 0.f, 0, 0);
      k_gemm<0, float, float, float><<<gs, 256, 0, stream>>>(
          qi, ki, sS + 3*kS2,  nullptr, kT, kT, kHD, kHD, kHD, kT, 1.f, 0.f, 0, 0);
      // fused softmax + fold -> P0,P1,P2 bf16
      k_smf<<<kT, 256, 0, stream>>>(sS, sP);
      // PV into fp32 attention-out block (rows b*kT, cols h*kHD)
      float* Cr = or_ + (long)b * kT * kD + h * kHD;
      float* Ci = oi  + (long)b * kT * kD + h * kHD;
      dim3 gv((kHD + 63) / 64, (kT + 63) / 64, 1);
      k_gemm<1, bf16, bf16, float><<<gv, 256, 0, stream>>>(
          sP,          vr, Cr, nullptr, kT, kHD, kT, kT, kHD, kD, 1.f, 0.f, 0, 0);
      k_gemm<1, bf16, bf16, float><<<gv, 256, 0, stream>>>(
          sP + 2*kS2,  vi, Cr, nullptr, kT, kHD, kT, kT, kHD, kD, 1.f, 0.f, 1, 0);
      k_gemm<1, bf16, bf16, float><<<gv, 256, 0, stream>>>(
          sP,          vi, Ci, nullptr, kT, kHD, kT, kT, kHD, kD, 1.f, 0.f, 0, 0);
      k_gemm<1, bf16, bf16, float><<<gv, 256, 0, stream>>>(
          sP + kS2,    vr, Ci, nullptr, kT, kHD, kT, kT, kHD, kD, 1.f, 0.f, 1, 0);
    }
  }

  // 4) output projection (tokens dead; write into T arena)
  gemm_fff(0, or_, attn_out_w, xr, nullptr,    kBS, kD, kD, kD, kD, kD, 1.f, 0.f, 0, 0);
  gemm_fff(0, oi,  attn_out_w, xi, attn_out_b, kBS, kD, kD, kD, kD, kD, 1.f, 2.f, 0, 0);

  // 5) LN1 (fp32, in T)
  k_ln<<<kBS, 256, 0, stream>>>(xr, n1_gr, n1_br, kD);
  k_ln<<<kBS, 256, 0, stream>>>(xi, n1_gi, n1_bi, kD);

  // 6) FFN layer1 -> bf16 hidden (hr over O arena, hi over S+PAD)
  {
    dim3 g((kDFF + 63) / 64, (kBS + 63) / 64, 1);
    k_gemm<0, float, float, bf16><<<g, 256, 0, stream>>>(
        xr, l1wr, hr, l1br, kBS, kDFF, kD, kD, kD, kDFF,  1.f,  1.f, 0, 0);
    k_gemm<0, float, float, bf16><<<g, 256, 0, stream>>>(
        xi, l1wi, hr, l1bi, kBS, kDFF, kD, kD, kD, kDFF, -1.f, -1.f, 1, 1);
    k_gemm<0, float, float, bf16><<<g, 256, 0, stream>>>(
        xi, l1wr, hi, l1br, kBS, kDFF, kD, kD, kD, kDFF,  1.f,  1.f, 0, 0);
    k_gemm<0, float, float, bf16><<<g, 256, 0, stream>>>(
        xr, l1wi, hi, l1bi, kBS, kDFF, kD, kD, kD, kDFF,  1.f,  1.f, 1, 1);
  }

  // 7) FFN layer2 -> fp32 out (back into T arena; xr/xi dead after layer1)
  {
    dim3 g((kD + 63) / 64, (kBS + 63) / 64, 1);
    k_gemm<0, bf16, float, float><<<g, 256, 0, stream>>>(
        hr, l2wr, xr, l2br, kBS, kD, kDFF, kDFF, kDFF, kD,  1.f,  1.f, 0, 0);
    k_gemm<0, bf16, float, float><<<g, 256, 0, stream>>>(
        hi, l2wi, xr, l2bi, kBS, kD, kDFF, kDFF, kDFF, kD, -1.f, -1.f, 1, 0);
    k_gemm<0, bf16, float, float><<<g, 256, 0, stream>>>(
        hi, l2wr, xi, l2br, kBS, kD, kDFF, kDFF, kDFF, kD,  1.f,  1.f, 0, 0);
    k_gemm<0, bf16, float, float><<<g, 256, 0, stream>>>(
        hr, l2wi, xi, l2bi, kBS, kD, kDFF, kDFF, kDFF, kD,  1.f,  1.f, 1, 0);
  }

  // 8) LN2 (fp32, in T)
  k_ln<<<kBS, 256, 0, stream>>>(xr, n2_gr, n2_br, kD);
  k_ln<<<kBS, 256, 0, stream>>>(xi, n2_gi, n2_bi, kD);

  // 9) mask + gate spec in-place (out1 holds final spec2)
  k_mask<<<(nct + 255) / 256, 256, 0, stream>>>(xr, xi, c2wr, c2br, c2wi,
                                                c2bi, spec);

  // 10) iSTFT (frames over O arena; hidden dead) + overlap-add -> out0
  k_istft<<<dim3(kT, kNSIG), 256, 0, stream>>>(spec, window, frames);
  k_gather<<<(int)(((long)kNSIG * kL + 255) / 256), 256, 0, stream>>>(
      frames, window, out0);
}

// Round 7
// 22472.893 us; speedup vs baseline: 2.0549x; 2.0549x over previous
//
#include <hip/hip_runtime.h>
#include <hip/hip_bf16.h>
#include <math.h>

#ifndef M_PIf
#define M_PIf 3.14159265358979323846f
#endif

static constexpr int kNFFT = 2048;
static constexpr int kHOP  = 512;
static constexpr int kBINS = 1025;
static constexpr int kT    = 862;     // frames == sequence length
static constexpr int kL    = 441000;
static constexpr int kB    = 4;
static constexpr int kNSIG = 8;       // B * 2 channels
static constexpr int kD    = 2050;
static constexpr int kHD   = 1025;    // head dim
static constexpr int kDFF  = 8200;
static constexpr int kBS   = kB * kT; // 3448 token rows
static constexpr int kD3   = 3 * kD;  // 6150
static constexpr float kAttnScale = 0.031234752377721214f; // 1/sqrt(1025)
static constexpr long kQK  = (long)kT * kHD;   // 883,550
static constexpr long kS2  = (long)kT * kT;    // 743,044

using bf16 = __hip_bfloat16;
typedef __attribute__((ext_vector_type(4))) float f32x4;
typedef __attribute__((ext_vector_type(8))) short bf16x8;

__device__ __forceinline__ float ldf(const float* p, long i) { return p[i]; }
__device__ __forceinline__ float ldf(const bf16* p, long i) {
  return __bfloat162float(p[i]);
}
__device__ __forceinline__ void sto(float* p, long i, float v) { p[i] = v; }
__device__ __forceinline__ void sto(bf16* p, long i, float v) {
  p[i] = __float2bfloat16(v);
}

// ---------------------------------------------------------------------------
// 2048-point radix-2 Stockham FFT in LDS (natural order in/out).
// ---------------------------------------------------------------------------
__device__ __forceinline__ void fft2048_lds(float*& sr, float*& si,
                                            float* dr, float* di,
                                            int tid, float dir) {
  int s = 0;
  for (int Ns = 1; Ns < 2048; Ns <<= 1, ++s) {
#pragma unroll
    for (int q = 0; q < 4; ++q) {
      int j = tid + q * 256;          // 0..1023
      int base = j & (Ns - 1);
      int grp = j >> s;
      float ang = dir * M_PIf * (float)base / (float)Ns;
      float c, sn;
      sincosf(ang, &sn, &c);
      float ar = sr[j],       ai = si[j];
      float br = sr[j + 1024], bi = si[j + 1024];
      float tbr = br * c - bi * sn;
      float tbi = br * sn + bi * c;
      int o = (grp << (s + 1)) + base;
      dr[o]      = ar + tbr;  di[o]      = ai + tbi;
      dr[o + Ns] = ar - tbr;  di[o + Ns] = ai - tbi;
    }
    __syncthreads();
    float* t0 = sr; sr = dr; dr = t0;
    float* t1 = si; si = di; di = t1;
  }
}

// STFT: one block per (frame, signal). Writes interleaved (re,im) into out1.
__global__ __launch_bounds__(256) void k_stft(const float* __restrict__ mix,
                                              const float* __restrict__ win,
                                              float* __restrict__ spec) {
  __shared__ float b0r[2048], b0i[2048], b1r[2048], b1i[2048];
  int t = blockIdx.x, sig = blockIdx.y, tid = threadIdx.x;
  const float* x = mix + (long)sig * kL;
  for (int i = tid; i < 2048; i += 256) {
    int src = t * kHOP + i - 1024;
    if (src < 0) src = -src;
    if (src >= kL) src = 2 * kL - 2 - src;
    b0r[i] = x[src] * win[i];
    b0i[i] = 0.f;
  }
  __syncthreads();
  float* sr = b0r; float* si = b0i;
  fft2048_lds(sr, si, b1r, b1i, tid, -1.f);
  for (int k = tid; k < kBINS; k += 256) {
    long o = ((long)sig * kBINS + k) * kT + t;
    spec[o * 2]     = sr[k];
    spec[o * 2 + 1] = si[k];
  }
}

// iSTFT per-frame from interleaved spec: hermitian extend, iFFT, window.
__global__ __launch_bounds__(256) void k_istft(const float* __restrict__ spec,
                                               const float* __restrict__ win,
                                               float* __restrict__ frames) {
  __shared__ float b0r[2048], b0i[2048], b1r[2048], b1i[2048];
  int t = blockIdx.x, sig = blockIdx.y, tid = threadIdx.x;
  for (int k = tid; k < kBINS; k += 256) {
    long o = ((long)sig * kBINS + k) * kT + t;
    b0r[k] = spec[o * 2];
    b0i[k] = spec[o * 2 + 1];
  }
  __syncthreads();
  for (int k = 1025 + tid; k < 2048; k += 256) {
    b0r[k] = b0r[2048 - k];
    b0i[k] = -b0i[2048 - k];
  }
  __syncthreads();
  float* sr = b0r; float* si = b0i;
  fft2048_lds(sr, si, b1r, b1i, tid, +1.f);
  const float scale = 1.f / 2048.f;
  float* fo = frames + ((long)sig * kT + t) * 2048;
  for (int n = tid; n < 2048; n += 256) fo[n] = sr[n] * scale * win[n];
}

// Deterministic overlap-add gather (<=4 frames per output sample) + wsq div.
__global__ void k_gather(const float* __restrict__ frames,
                         const float* __restrict__ win,
                         float* __restrict__ out0) {
  long idx = (long)blockIdx.x * 256 + threadIdx.x;
  long total = (long)kNSIG * kL;
  if (idx >= total) return;
  int sig = (int)(idx / kL);
  int l = (int)(idx % kL);
  int j = l + 1024;
  int tmax = j >> 9; if (tmax > kT - 1) tmax = kT - 1;
  int v = j - 1536;
  int tmin = v > 0 ? (v >> 9) : 0;
  float acc = 0.f, w2 = 0.f;
  for (int t = tmin; t <= tmax; ++t) {
    int n = j - (t << 9);
    float w = win[n];
    acc += frames[((long)sig * kT + t) * 2048 + n];
    w2 = fmaf(w, w, w2);
  }
  out0[idx] = acc / (w2 > 1e-11f ? w2 : 1.f);
}

// conv1x1 (complex, per-channel) + transpose to (B,T,D) + positional enc.
__global__ void k_conv1_pe(const float* __restrict__ spec,
                           const float* __restrict__ c1wr, const float* __restrict__ c1br,
                           const float* __restrict__ c1wi, const float* __restrict__ c1bi,
                           float* __restrict__ xr, float* __restrict__ xi) {
  long idx = (long)blockIdx.x * 256 + threadIdx.x;
  long total = (long)kB * 2 * kBINS * kT;
  if (idx >= total) return;
  int t = (int)(idx % kT);
  long r0 = idx / kT;
  int bin = (int)(r0 % kBINS);
  long r1 = r0 / kBINS;
  int ch = (int)(r1 % 2);
  int b = (int)(r1 / 2);
  float re = spec[idx * 2], im = spec[idx * 2 + 1];
  float wr = c1wr[ch], br = c1br[ch], wi = c1wi[ch], bi = c1bi[ch];
  float nr = (re * wr + br) - (im * wi + bi);
  float ni = (im * wr + br) + (re * wi + bi);
  int d = bin * 2 + ch;
  int k = d >> 1;
  float dv = expf((float)k * (-9.210340371976184f / 1025.0f));
  float arg = (float)t * dv;
  float pe = (d & 1) ? cosf(arg) : sinf(arg);
  long ro = ((long)(b * kT + t)) * kD + d;
  xr[ro] = nr + pe;
  xi[ro] = ni + pe;
}

// ---------------------------------------------------------------------------
// fp32 VALU GEMM (kept for the numerically-critical Q/K/score path).
// BMODE=0: C = A*B^T (B NxK). Epilogue: v = sign*dot + bscale*bias[n];
// if accum v += C; if relu v = max(v,0).
// ---------------------------------------------------------------------------
template <int BMODE, typename TA, typename TB, typename TC>
__global__ __launch_bounds__(256) void k_gemm(
    const TA* __restrict__ A, const TB* __restrict__ B,
    TC* __restrict__ C, const float* __restrict__ bias,
    int M, int N, int K, int lda, int ldb, int ldc,
    float sign, float bscale, int accum, int relu) {
  __shared__ __align__(16) float As[16][64];
  __shared__ __align__(16) float Bs[16][64];
  int tid = threadIdx.x;
  int tx = tid & 15, ty = tid >> 4;
  int bm = blockIdx.y * 64, bn = blockIdx.x * 64;
  float acc[4][4] = {};
  for (int k0 = 0; k0 < K; k0 += 16) {
    {
      int row = tid >> 2, kq = (tid & 3) * 4;
      int gm = bm + row;
#pragma unroll
      for (int e = 0; e < 4; ++e) {
        int gk = k0 + kq + e;
        As[kq + e][row] = (gm < M && gk < K) ? ldf(A, (long)gm * lda + gk) : 0.f;
      }
    }
    if (BMODE == 0) {
      int row = tid >> 2, kq = (tid & 3) * 4;
      int gn = bn + row;
#pragma unroll
      for (int e = 0; e < 4; ++e) {
        int gk = k0 + kq + e;
        Bs[kq + e][row] = (gn < N && gk < K) ? ldf(B, (long)gn * ldb + gk) : 0.f;
      }
    } else {
      int kk = tid >> 4, nq = (tid & 15) * 4;
#pragma unroll
      for (int e = 0; e < 4; ++e) {
        int gn = bn + nq + e;
        Bs[kk][nq + e] =
            ((k0 + kk) < K && gn < N) ? ldf(B, (long)(k0 + kk) * ldb + gn) : 0.f;
      }
    }
    __syncthreads();
#pragma unroll
    for (int kk = 0; kk < 16; ++kk) {
      const float4 av = *(const float4*)&As[kk][ty * 4];
      const float4 bv = *(const float4*)&Bs[kk][tx * 4];
      float a4[4] = {av.x, av.y, av.z, av.w};
      float b4[4] = {bv.x, bv.y, bv.z, bv.w};
#pragma unroll
      for (int i = 0; i < 4; ++i)
#pragma unroll
        for (int jj = 0; jj < 4; ++jj)
          acc[i][jj] = fmaf(a4[i], b4[jj], acc[i][jj]);
    }
    __syncthreads();
  }
#pragma unroll
  for (int i = 0; i < 4; ++i) {
    int gm = bm + ty * 4 + i;
    if (gm >= M) continue;
#pragma unroll
    for (int jj = 0; jj < 4; ++jj) {
      int gn = bn + tx * 4 + jj;
      if (gn >= N) continue;
      float v = sign * acc[i][jj];
      if (bias) v += bscale * bias[gn];
      long co = (long)gm * ldc + gn;
      if (accum) v += ldf(C, co);
      if (relu) v = fmaxf(v, 0.f);
      sto(C, co, v);
    }
  }
}

// ---------------------------------------------------------------------------
// bf16 MFMA GEMM (16x16x32), fp32 accumulate. 128x128 tile, BK=32, 4 waves,
// each wave owns a 64x64 sub-tile = 4x4 fragments. Inputs converted fp32->
// bf16 during LDS staging (lossless for bf16 inputs). LDS padded to [128][40]
// (row stride 80 B -> 2-way bank aliasing, free per m136).
// BMODE=0: B is NxK (C=A*B^T);  BMODE=1: B is KxN.
// Epilogue identical to k_gemm.
// ---------------------------------------------------------------------------
template <int BMODE, typename TA, typename TB, typename TC>
__global__ __launch_bounds__(256) void k_mfma(
    const TA* __restrict__ A, const TB* __restrict__ B,
    TC* __restrict__ C, const float* __restrict__ bias,
    int M, int N, int K, int lda, int ldb, int ldc,
    float sign, float bscale, int accum, int relu) {
  __shared__ __align__(16) bf16 As[128][40];
  __shared__ __align__(16) bf16 Bs[128][40];
  int tid = threadIdx.x;
  int bm = blockIdx.y * 128, bn = blockIdx.x * 128;
  int lane = tid & 63, w = tid >> 6;
  int wr = (w >> 1) * 64, wc = (w & 1) * 64;   // wave sub-tile origin
  int fr = lane & 15;                          // fragment row/col
  int fq = lane >> 4;                          // quad index
  f32x4 acc[4][4] = {};

  int sr = tid >> 1;            // staging row 0..127
  int sk = (tid & 1) * 16;      // staging k offset 0/16

  for (int k0 = 0; k0 < K; k0 += 32) {
    // ---- stage A (row-major MxK) -> As[r][k] bf16
    {
      int gm = bm + sr;
      bf16 tmp[16];
      if (gm < M && k0 + sk + 15 < K) {
        const TA* src = A + (long)gm * lda + k0 + sk;
#pragma unroll
        for (int e = 0; e < 16; ++e) tmp[e] = __float2bfloat16(ldf(src, e));
      } else {
#pragma unroll
        for (int e = 0; e < 16; ++e) {
          int gk = k0 + sk + e;
          tmp[e] = __float2bfloat16(
              (gm < M && gk < K) ? ldf(A, (long)gm * lda + gk) : 0.f);
        }
      }
      *(bf16x8*)&As[sr][sk]     = *(bf16x8*)&tmp[0];
      *(bf16x8*)&As[sr][sk + 8] = *(bf16x8*)&tmp[8];
    }
    // ---- stage B -> Bs[n][k] bf16
    if (BMODE == 0) {
      int gn = bn + sr;
      bf16 tmp[16];
      if (gn < N && k0 + sk + 15 < K) {
        const TB* src = B + (long)gn * ldb + k0 + sk;
#pragma unroll
        for (int e = 0; e < 16; ++e) tmp[e] = __float2bfloat16(ldf(src, e));
      } else {
#pragma unroll
        for (int e = 0; e < 16; ++e) {
          int gk = k0 + sk + e;
          tmp[e] = __float2bfloat16(
              (gn < N && gk < K) ? ldf(B, (long)gn * ldb + gk) : 0.f);
        }
      }
      *(bf16x8*)&Bs[sr][sk]     = *(bf16x8*)&tmp[0];
      *(bf16x8*)&Bs[sr][sk + 8] = *(bf16x8*)&tmp[8];
    } else {
      int kk = tid >> 3;          // 0..31
      int nq = (tid & 7) * 16;    // 0..112
      int gk = k0 + kk;
      if (gk < K && bn + nq + 15 < N) {
        const TB* src = B + (long)gk * ldb + bn + nq;
#pragma unroll
        for (int e = 0; e < 16; ++e)
          Bs[nq + e][kk] = __float2bfloat16(ldf(src, e));
      } else {
#pragma unroll
        for (int e = 0; e < 16; ++e) {
          int gn = bn + nq + e;
          Bs[nq + e][kk] = __float2bfloat16(
              (gk < K && gn < N) ? ldf(B, (long)gk * ldb + gn) : 0.f);
        }
      }
    }
    __syncthreads();
    // ---- compute: 16 MFMA per wave
    bf16x8 a[4], b[4];
#pragma unroll
    for (int i = 0; i < 4; ++i)
      a[i] = *(const bf16x8*)&As[wr + i * 16 + fr][fq * 8];
#pragma unroll
    for (int j = 0; j < 4; ++j)
      b[j] = *(const bf16x8*)&Bs[wc + j * 16 + fr][fq * 8];
#pragma unroll
    for (int i = 0; i < 4; ++i)
#pragma unroll
      for (int j = 0; j < 4; ++j)
        acc[i][j] = __builtin_amdgcn_mfma_f32_16x16x32_bf16(
            a[i], b[j], acc[i][j], 0, 0, 0);
    __syncthreads();
  }
  // ---- epilogue: C/D layout col=lane&15, row=4*(lane>>4)+reg
#pragma unroll
  for (int i = 0; i < 4; ++i) {
#pragma unroll
    for (int j = 0; j < 4; ++j) {
      int gn = bn + wc + j * 16 + fr;
      if (gn >= N) continue;
      float bv = bias ? bscale * bias[gn] : 0.f;
#pragma unroll
      for (int r = 0; r < 4; ++r) {
        int gm = bm + wr + i * 16 + fq * 4 + r;
        if (gm >= M) continue;
        float v = sign * acc[i][j][r] + bv;
        long co = (long)gm * ldc + gn;
        if (accum) v += ldf(C, co);
        if (relu) v = fmaxf(v, 0.f);
        sto(C, co, v);
      }
    }
  }
}

// Per-head fused softmax over 4 fp32 score mats (stride kS2) + fold into
// 3 bf16 prob mats: P0=M1=Arr-Aii, P1=M2p=Ari+Air, P2=M2m=Ari-Air.
__global__ __launch_bounds__(256) void k_smf(const float* __restrict__ S,
                                             bf16* __restrict__ P) {
  long rbase = (long)blockIdx.x * kT;
  int tid = threadIdx.x;
  int lane = tid & 63, w = tid >> 6;
  float v[4][4];
  float mx[4] = {-3.4e38f, -3.4e38f, -3.4e38f, -3.4e38f};
#pragma unroll
  for (int c = 0; c < 4; ++c) {
    const float* row = S + c * kS2 + rbase;
#pragma unroll
    for (int q = 0; q < 4; ++q) {
      int i = tid + q * 256;
      v[c][q] = (i < kT) ? row[i] : -3.4e38f;
      mx[c] = fmaxf(mx[c], v[c][q]);
    }
  }
  __shared__ float redm[4][4];
  for (int o = 32; o > 0; o >>= 1)
#pragma unroll
    for (int c = 0; c < 4; ++c) mx[c] = fmaxf(mx[c], __shfl_down(mx[c], o));
  if (lane == 0)
#pragma unroll
    for (int c = 0; c < 4; ++c) redm[w][c] = mx[c];
  __syncthreads();
#pragma unroll
  for (int c = 0; c < 4; ++c)
    mx[c] = fmaxf(fmaxf(redm[0][c], redm[1][c]), fmaxf(redm[2][c], redm[3][c]));
  __syncthreads();
  float sm[4] = {0.f, 0.f, 0.f, 0.f};
#pragma unroll
  for (int c = 0; c < 4; ++c)
#pragma unroll
    for (int q = 0; q < 4; ++q) {
      int i = tid + q * 256;
      if (i < kT) {
        v[c][q] = expf(kAttnScale * (v[c][q] - mx[c]));
        sm[c] += v[c][q];
      }
    }
  __shared__ float reds[4][4];
  for (int o = 32; o > 0; o >>= 1)
#pragma unroll
    for (int c = 0; c < 4; ++c) sm[c] += __shfl_down(sm[c], o);
  if (lane == 0)
#pragma unroll
    for (int c = 0; c < 4; ++c) reds[w][c] = sm[c];
  __syncthreads();
  float inv[4];
#pragma unroll
  for (int c = 0; c < 4; ++c)
    inv[c] = 1.f / (reds[0][c] + reds[1][c] + reds[2][c] + reds[3][c]);
  bf16* p0 = P + rbase;
  bf16* p1 = P + kS2 + rbase;
  bf16* p2 = P + 2 * kS2 + rbase;
#pragma unroll
  for (int q = 0; q < 4; ++q) {
    int i = tid + q * 256;
    if (i >= kT) continue;
    float a0 = v[0][q] * inv[0], a1 = v[1][q] * inv[1];
    float a2 = v[2][q] * inv[2], a3 = v[3][q] * inv[3];
    p0[i] = __float2bfloat16(a0 - a3);
    p1[i] = __float2bfloat16(a1 + a2);
    p2[i] = __float2bfloat16(a1 - a2);
  }
}

// LayerNorm over rows of length d, in place (fp32).
__global__ __launch_bounds__(256) void k_ln(float* __restrict__ X,
                                            const float* __restrict__ g,
                                            const float* __restrict__ b, int d) {
  long row = blockIdx.x;
  float* x = X + row * d;
  int tid = threadIdx.x;
  float s = 0.f, s2 = 0.f;
  for (int i = tid; i < d; i += 256) {
    float v = x[i];
    s += v;
    s2 = fmaf(v, v, s2);
  }
  __shared__ float rs[4], rs2[4];
  for (int o = 32; o > 0; o >>= 1) {
    s += __shfl_down(s, o);
    s2 += __shfl_down(s2, o);
  }
  int lane = tid & 63, w = tid >> 6;
  if (lane == 0) { rs[w] = s; rs2[w] = s2; }
  __syncthreads();
  float st = rs[0] + rs[1] + rs[2] + rs[3];
  float s2t = rs2[0] + rs2[1] + rs2[2] + rs2[3];
  float m = st / d;
  float var = s2t / d - m * m;
  float inv = rsqrtf(var + 1e-5f);
  for (int i = tid; i < d; i += 256) x[i] = (x[i] - m) * inv * g[i] + b[i];
}

// Final complex conv1x1 mask + sigmoid gating of spec (in-place in out1).
__global__ void k_mask(const float* __restrict__ gr_, const float* __restrict__ gi_,
                       const float* __restrict__ c2wr, const float* __restrict__ c2br,
                       const float* __restrict__ c2wi, const float* __restrict__ c2bi,
                       float* __restrict__ spec) {
  long idx = (long)blockIdx.x * 256 + threadIdx.x;
  long total = (long)kB * 2 * kBINS * kT;
  if (idx >= total) return;
  int t = (int)(idx % kT);
  long r0 = idx / kT;
  int bin = (int)(r0 % kBINS);
  long r1 = r0 / kBINS;
  int ch = (int)(r1 % 2);
  int b = (int)(r1 / 2);
  long ro = ((long)(b * kT + t)) * kD + (bin * 2 + ch);
  float gr = gr_[ro], gi = gi_[ro];
  float wr = c2wr[ch], br = c2br[ch], wi = c2wi[ch], bi = c2bi[ch];
  float mr = (gr * wr + br) - (gi * wi + bi);
  float mi = (gi * wr + br) + (gr * wi + bi);
  float re = spec[idx * 2], im = spec[idx * 2 + 1];
  spec[idx * 2]     = re / (1.f + expf(-mr));
  spec[idx * 2 + 1] = im / (1.f + expf(-mi));
}

extern "C" void kernel_launch(void* const* d_in, const int* in_sizes, int n_in,
                              void* d_out, int out_size, void* d_ws, size_t ws_size,
                              hipStream_t stream) {
  const float* mix        = (const float*)d_in[0];
  const float* window     = (const float*)d_in[1];
  const float* c1wr       = (const float*)d_in[2];
  const float* c1br       = (const float*)d_in[3];
  const float* c1wi       = (const float*)d_in[4];
  const float* c1bi       = (const float*)d_in[5];
  const float* c2wr       = (const float*)d_in[6];
  const float* c2br       = (const float*)d_in[7];
  const float* c2wi       = (const float*)d_in[8];
  const float* c2bi       = (const float*)d_in[9];
  const float* attn_in_w  = (const float*)d_in[10];
  const float* attn_in_b  = (const float*)d_in[11];
  const float* attn_out_w = (const float*)d_in[12];
  const float* attn_out_b = (const float*)d_in[13];
  const float* l1wr       = (const float*)d_in[14];
  const float* l1br       = (const float*)d_in[15];
  const float* l1wi       = (const float*)d_in[16];
  const float* l1bi       = (const float*)d_in[17];
  const float* l2wr       = (const float*)d_in[18];
  const float* l2br       = (const float*)d_in[19];
  const float* l2wi       = (const float*)d_in[20];
  const float* l2bi       = (const float*)d_in[21];
  const float* n1_gr      = (const float*)d_in[22];
  const float* n1_br      = (const float*)d_in[23];
  const float* n1_gi      = (const float*)d_in[24];
  const float* n1_bi      = (const float*)d_in[25];
  const float* n2_gr      = (const float*)d_in[26];
  const float* n2_br      = (const float*)d_in[27];
  const float* n2_gi      = (const float*)d_in[28];
  const float* n2_bi      = (const float*)d_in[29];

  // ---- Workspace arenas (bytes). Total 169,641,600 B (< 188.9 MB proven).
  // [T 56,547,200][O 56,547,200][S 34,017,968][PAD 22,529,232]
  char* wsb = (char*)d_ws;
  const size_t oT   = 0;
  const size_t oO   = 56547200;
  const size_t oS   = 113094400;
  const size_t kNeed = 169641600;
  if (ws_size < kNeed) return;  // fail signature: out0 all-zero (2.578125)

  float* xr  = (float*)(wsb + oT);            // tokens r (later: proj/FFN2 out)
  float* xi  = xr + 7068400L;
  float* or_ = (float*)(wsb + oO);            // attention out r (fp32)
  float* oi  = or_ + 7068400L;
  // per-head scratch inside S:
  float* qr = (float*)(wsb + oS);             // 883,550 f32 each
  float* qi = qr + kQK;
  float* kr = qi + kQK;
  float* ki = kr + kQK;
  bf16*  vr = (bf16*)(wsb + oS + 14136800);   // 883,550 bf16 each
  bf16*  vi = (bf16*)(wsb + oS + 15903900);
  float* sS = (float*)(wsb + oS + 17671000);  // 4 x 743,044 f32
  bf16*  sP = (bf16*)(wsb + oS + 29559704);   // 3 x 743,044 bf16
  // phase-2 overlays:
  bf16*  hr = (bf16*)(wsb + oO);              // 28,273,600 bf16 = O arena
  bf16*  hi = (bf16*)(wsb + oS);              // 28,273,600 bf16 = S+PAD
  float* frames = (float*)(wsb + oO);         // 14,123,008 f32 (< O arena)

  float* out0 = (float*)d_out;
  float* spec = out0 + (long)kNSIG * kL;  // out1: interleaved (re,im)

  // 1) STFT -> spec (out1)
  k_stft<<<dim3(kT, kNSIG), 256, 0, stream>>>(mix, window, spec);

  // 2) conv1 + pos-enc -> fp32 tokens (T arena)
  long nct = (long)kB * 2 * kBINS * kT;
  k_conv1_pe<<<(nct + 255) / 256, 256, 0, stream>>>(spec, c1wr, c1br, c1wi,
                                                    c1bi, xr, xi);

  // 3) streaming attention, one (b,h) at a time; fp32 Q/K/scores.
  for (int b = 0; b < kB; ++b) {
    const float* xrb = xr + (long)b * kT * kD;
    const float* xib = xi + (long)b * kT * kD;
    for (int h = 0; h < 2; ++h) {
      const float* Wq = attn_in_w + (long)(h * kHD) * kD;
      const float* Wk = attn_in_w + (long)(kD + h * kHD) * kD;
      const float* Wv = attn_in_w + (long)(2 * kD + h * kHD) * kD;
      const float* bq = attn_in_b + h * kHD;
      const float* bk = attn_in_b + kD + h * kHD;
      const float* bv = attn_in_b + 2 * kD + h * kHD;
      // Q,K projections: fp32 VALU (argmax-critical)
      dim3 gp((kHD + 63) / 64, (kT + 63) / 64, 1);
      k_gemm<0, float, float, float><<<gp, 256, 0, stream>>>(
          xrb, Wq, qr, bq, kT, kHD, kD, kD, kD, kHD, 1.f, 1.f, 0, 0);
      k_gemm<0, float, float, float><<<gp, 256, 0, stream>>>(
          xib, Wq, qi, bq, kT, kHD, kD, kD, kD, kHD, 1.f, 1.f, 0, 0);
      k_gemm<0, float, float, float><<<gp, 256, 0, stream>>>(
          xrb, Wk, kr, bk, kT, kHD, kD, kD, kD, kHD, 1.f, 1.f, 0, 0);
      k_gemm<0, float, float, float><<<gp, 256, 0, stream>>>(
          xib, Wk, ki, bk, kT, kHD, kD, kD, kD, kHD, 1.f, 1.f, 0, 0);
      // V projection: MFMA bf16
      dim3 gpm((kHD + 127) / 128, (kT + 127) / 128, 1);
      k_mfma<0, float, float, bf16><<<gpm, 256, 0, stream>>>(
          xrb, Wv, vr, bv, kT, kHD, kD, kD, kD, kHD, 1.f, 1.f, 0, 0);
      k_mfma<0, float, float, bf16><<<gpm, 256, 0, stream>>>(
          xib, Wv, vi, bv, kT, kHD, kD, kD, kD, kHD, 1.f, 1.f, 0, 0);
      // scores: rr, ri, ir, ii (fp32 VALU)
      dim3 gs((kT + 63) / 64, (kT + 63) / 64, 1);
      k_gemm<0, float, float, float><<<gs, 256, 0, stream>>>(
          qr, kr, sS,          nullptr, kT, kT, kHD, kHD, kHD, kT, 1.f, 0.f, 0, 0);
      k_gemm<0, float, float, float><<<gs, 256, 0, stream>>>(
          qr, ki, sS + kS2,    nullptr, kT, kT, kHD, kHD, kHD, kT, 1.f, 0.f, 0, 0);
      k_gemm<0, float, float, float><<<gs, 256, 0, stream>>>(
          qi, kr, sS + 2*kS2,  nullptr, kT, kT, kHD, kHD, kHD, kT, 1.f, 0.f, 0, 0);
      k_gemm<0, float, float, float><<<gs, 256, 0, stream>>>(
          qi, ki, sS + 3*kS2,  nullptr, kT, kT, kHD, kHD, kHD, kT, 1.f, 0.f, 0, 0);
      // fused softmax + fold -> P0,P1,P2 bf16
      k_smf<<<kT, 256, 0, stream>>>(sS, sP);
      // PV into fp32 attention-out block: MFMA bf16 (B KxN -> BMODE=1)
      float* Cr = or_ + (long)b * kT * kD + h * kHD;
      float* Ci = oi  + (long)b * kT * kD + h * kHD;
      dim3 gv((kHD + 127) / 128, (kT + 127) / 128, 1);
      k_mfma<1, bf16, bf16, float><<<gv, 256, 0, stream>>>(
          sP,          vr, Cr, nullptr, kT, kHD, kT, kT, kHD, kD, 1.f, 0.f, 0, 0);
      k_mfma<1, bf16, bf16, float><<<gv, 256, 0, stream>>>(
          sP + 2*kS2,  vi, Cr, nullptr, kT, kHD, kT, kT, kHD, kD, 1.f, 0.f, 1, 0);
      k_mfma<1, bf16, bf16, float><<<gv, 256, 0, stream>>>(
          sP,          vi, Ci, nullptr, kT, kHD, kT, kT, kHD, kD, 1.f, 0.f, 0, 0);
      k_mfma<1, bf16, bf16, float><<<gv, 256, 0, stream>>>(
          sP + kS2,    vr, Ci, nullptr, kT, kHD, kT, kT, kHD, kD, 1.f, 0.f, 1, 0);
    }
  }

  // 4) output projection: MFMA bf16 (tokens dead; write into T arena)
  {
    dim3 g((kD + 127) / 128, (kBS + 127) / 128, 1);
    k_mfma<0, float, float, float><<<g, 256, 0, stream>>>(
        or_, attn_out_w, xr, nullptr,    kBS, kD, kD, kD, kD, kD, 1.f, 0.f, 0, 0);
    k_mfma<0, float, float, float><<<g, 256, 0, stream>>>(
        oi,  attn_out_w, xi, attn_out_b, kBS, kD, kD, kD, kD, kD, 1.f, 2.f, 0, 0);
  }

  // 5) LN1 (fp32, in T)
  k_ln<<<kBS, 256, 0, stream>>>(xr, n1_gr, n1_br, kD);
  k_ln<<<kBS, 256, 0, stream>>>(xi, n1_gi, n1_bi, kD);

  // 6) FFN layer1 -> bf16 hidden: MFMA (hr over O arena, hi over S+PAD)
  {
    dim3 g((kDFF + 127) / 128, (kBS + 127) / 128, 1);
    k_mfma<0, float, float, bf16><<<g, 256, 0, stream>>>(
        xr, l1wr, hr, l1br, kBS, kDFF, kD, kD, kD, kDFF,  1.f,  1.f, 0, 0);
    k_mfma<0, float, float, bf16><<<g, 256, 0, stream>>>(
        xi, l1wi, hr, l1bi, kBS, kDFF, kD, kD, kD, kDFF, -1.f, -1.f, 1, 1);
    k_mfma<0, float, float, bf16><<<g, 256, 0, stream>>>(
        xi, l1wr, hi, l1br, kBS, kDFF, kD, kD, kD, kDFF,  1.f,  1.f, 0, 0);
    k_mfma<0, float, float, bf16><<<g, 256, 0, stream>>>(
        xr, l1wi, hi, l1bi, kBS, kDFF, kD, kD, kD, kDFF,  1.f,  1.f, 1, 1);
  }

  // 7) FFN layer2 -> fp32 out: MFMA (back into T arena)
  {
    dim3 g((kD + 127) / 128, (kBS + 127) / 128, 1);
    k_mfma<0, bf16, float, float><<<g, 256, 0, stream>>>(
        hr, l2wr, xr, l2br, kBS, kD, kDFF, kDFF, kDFF, kD,  1.f,  1.f, 0, 0);
    k_mfma<0, bf16, float, float><<<g, 256, 0, stream>>>(
        hi, l2wi, xr, l2bi, kBS, kD, kDFF, kDFF, kDFF, kD, -1.f, -1.f, 1, 0);
    k_mfma<0, bf16, float, float><<<g, 256, 0, stream>>>(
        hi, l2wr, xi, l2br, kBS, kD, kDFF, kDFF, kDFF, kD,  1.f,  1.f, 0, 0);
    k_mfma<0, bf16, float, float><<<g, 256, 0, stream>>>(
        hr, l2wi, xi, l2bi, kBS, kD, kDFF, kDFF, kDFF, kD,  1.f,  1.f, 1, 0);
  }

  // 8) LN2 (fp32, in T)
  k_ln<<<kBS, 256, 0, stream>>>(xr, n2_gr, n2_br, kD);
  k_ln<<<kBS, 256, 0, stream>>>(xi, n2_gi, n2_bi, kD);

  // 9) mask + gate spec in-place (out1 holds final spec2)
  k_mask<<<(nct + 255) / 256, 256, 0, stream>>>(xr, xi, c2wr, c2br, c2wi,
                                                c2bi, spec);

  // 10) iSTFT (frames over O arena; hidden dead) + overlap-add -> out0
  k_istft<<<dim3(kT, kNSIG), 256, 0, stream>>>(spec, window, frames);
  k_gather<<<(int)(((long)kNSIG * kL + 255) / 256), 256, 0, stream>>>(
      frames, window, out0);
}